// Round 12
// baseline (312.873 us; speedup 1.0000x reference)
//
#include <hip/hip_runtime.h>
#include <hip/hip_bf16.h>
#include <stdint.h>

// Problem constants
#define Bsz 2048
#define Ssz 200
#define Dsz 128

typedef __attribute__((ext_vector_type(8))) short short8;
typedef __attribute__((ext_vector_type(4))) float f32x4;
typedef unsigned short ushort_t;
typedef unsigned int uint_t;

// ---- scores kernel LDS (total 37,888) ----
#define KEYS_OFF   0        // [112][128] bf16, XOR-swizzled  28,672
#define H1S_OFF    28672    // [4 waves][16][64] bf16          8,192
#define C1S_OFF    36864    // [256] f32                       1,024
#define SMEM_A     37888

__device__ __forceinline__ ushort_t cvtbf(float x) {
    __hip_bfloat16 h = __float2bfloat16(x);   // RTNE; pairs into v_cvt_pk_bf16_f32
    ushort_t u;
    __builtin_memcpy(&u, &h, 2);
    return u;
}

// ---------- prep: fold W1 (sum/c/diff row-major), transpose Wo, cast W2 ----------
__global__ void prep_kernel(const float* __restrict__ W1, const float* __restrict__ W2,
                            const float* __restrict__ Wo,
                            float* __restrict__ W1sum, float* __restrict__ W1c,
                            float* __restrict__ W1diffR, float* __restrict__ WoT,
                            ushort_t* __restrict__ W2bf) {
    int i = blockIdx.x * blockDim.x + threadIdx.x;
    if (i < 32768) {                       // n in [0,256), j in [0,128)
        int n = i >> 7, j = i & 127;
        float a  = W1[n * 512 + j];        // keys part
        float dd = W1[n * 512 + 384 + j];  // (k - q) part
        W1sum[i] = a + dd;                 // coeff of k
        W1c[i]   = W1[n * 512 + 256 + j];  // coeff of k*q
        W1diffR[i] = W1[n * 512 + 128 + j] - dd;  // coeff of q (row-major)
    }
    if (i < 16384) {                       // WoT[j][d] = Wo[d][j]
        int j = i >> 7, d = i & 127;
        WoT[i] = Wo[d * 128 + j];
    }
    if (i < 8192) W2bf[i] = cvtbf(W2[i]); // flat [h][e][k], k fastest
}

// ---------- per-b: c1 bias + folded layer-1 weight in MFMA-fragment order ----------
// W1g2[b] layout: slot o in [0,4096): t4=o>>10, lk=(o>>8)&3, n=o&255
//   holds bf16x8 of W1eff[n][t4*32+lk*8 .. +8]; W1eff = W1sum + W1c*q[b]
__global__ void w1effc1_kernel(const float* __restrict__ query, const float* __restrict__ W1sum,
                               const float* __restrict__ W1c, const float* __restrict__ W1diffR,
                               const float* __restrict__ b1,
                               ushort_t* __restrict__ W1g2, float* __restrict__ c1out) {
    __shared__ float qs[128];
    int b = blockIdx.x, t = threadIdx.x;
    if (t < 128) qs[t] = query[b * 128 + t];
    __syncthreads();
    // c1[n] = b1[n] + dot(W1diffR[n], q)
    {
        float acc = b1[t];
        const float4* wr  = (const float4*)(W1diffR + t * 128);
        const float4* qv4 = (const float4*)qs;
        #pragma unroll 8
        for (int j4 = 0; j4 < 32; ++j4) {
            float4 wv = wr[j4];
            float4 qq = qv4[j4];
            acc += wv.x * qq.x + wv.y * qq.y + wv.z * qq.z + wv.w * qq.w;
        }
        c1out[b * 256 + t] = acc;
    }
    // fold: out-slot-major so writes are fully coalesced
    ushort_t* wout = W1g2 + ((size_t)b << 15);
    #pragma unroll 2
    for (int it = 0; it < 16; ++it) {
        int o  = t + 256 * it;
        int t4 = o >> 10, lk = (o >> 8) & 3, n = o & 255;
        int k0 = t4 * 32 + lk * 8;
        const float4* ps = (const float4*)(W1sum + n * 128 + k0);
        const float4* pc = (const float4*)(W1c + n * 128 + k0);
        const float4* pq = (const float4*)(qs + k0);
        float4 s0 = ps[0], s1 = ps[1];
        float4 c0 = pc[0], c1f = pc[1];
        float4 q0 = pq[0], q1 = pq[1];
        short8 ov;
        ov[0] = (short)cvtbf(s0.x + c0.x * q0.x);
        ov[1] = (short)cvtbf(s0.y + c0.y * q0.y);
        ov[2] = (short)cvtbf(s0.z + c0.z * q0.z);
        ov[3] = (short)cvtbf(s0.w + c0.w * q0.w);
        ov[4] = (short)cvtbf(s1.x + c1f.x * q1.x);
        ov[5] = (short)cvtbf(s1.y + c1f.y * q1.y);
        ov[6] = (short)cvtbf(s1.z + c1f.z * q1.z);
        ov[7] = (short)cvtbf(s1.w + c1f.w * q1.w);
        *(short8*)(wout + (size_t)o * 8) = ov;
    }
}

// ---------- per-b bias only (fallback path) ----------
__global__ void c1_kernel(const float* __restrict__ query, const float* __restrict__ W1diffR,
                          const float* __restrict__ b1, float* __restrict__ c1out) {
    int b = blockIdx.x, n = threadIdx.x;
    float acc = b1[n];
    const float4* wr  = (const float4*)(W1diffR + n * 128);
    const float4* qv4 = (const float4*)(query + b * 128);
    #pragma unroll 8
    for (int j4 = 0; j4 < 32; ++j4) {
        float4 wv = wr[j4];
        float4 qq = qv4[j4];
        acc += wv.x * qq.x + wv.y * qq.y + wv.z * qq.z + wv.w * qq.w;
    }
    c1out[b * 256 + n] = acc;
}

// ================= shared score-pipeline body (macro-free, inlined twice) =============
// Everything after bfr is available. Kept identical between the two kernels.
__device__ __forceinline__ void scores_body(char* smem, const short8* bfr,
                                            const int* kmask,
                                            const float* a1, const float* b2,
                                            const float* a2, const float* W3,
                                            const float* b3, const ushort_t* W2bf,
                                            const float* c1ws, float* scores_ws,
                                            int bb, int half, int w, int l15, int lk) {
    float* c1s = (float*)(smem + C1S_OFF);
    const int rbase = half * 112;

    const float a1v = a1[w];
    const float a2v = a2[w];
    const float b3v = b3[w];
    float b2v[2], w3v[2];
    #pragma unroll
    for (int nt = 0; nt < 2; ++nt) {
        b2v[nt] = b2[w * 32 + nt * 16 + l15];
        w3v[nt] = W3[w * 32 + nt * 16 + l15];
    }
    short8 w2f[2][2];
    #pragma unroll
    for (int kt = 0; kt < 2; ++kt)
        #pragma unroll
        for (int nt = 0; nt < 2; ++nt)
            w2f[kt][nt] = *(const short8*)(W2bf + w * 2048 + (nt * 16 + l15) * 64 + kt * 32 + lk * 8);

    __syncthreads();   // the ONLY barrier: keys + c1 staged

    float c1v[4];
    #pragma unroll
    for (int nt = 0; nt < 4; ++nt) c1v[nt] = c1s[w * 64 + nt * 16 + l15];

    const f32x4 fz = {0.f, 0.f, 0.f, 0.f};
    char* h1b = smem + H1S_OFF + w * 2048;     // wave-private [16][64] bf16
    const int ntiles = 7 - half;               // 7 tiles (rows 0-111) or 6 (112-207)

    #pragma unroll 1
    for (int mi = 0; mi < ntiles; ++mi) {
        f32x4 acc[4];
        #pragma unroll
        for (int nt = 0; nt < 4; ++nt) acc[nt] = fz;

        #pragma unroll
        for (int t = 0; t < 4; ++t) {
            int lrow = mi * 16 + l15;          // local staged row
            int off = KEYS_OFF + (((lrow << 8) + (t * 64 + lk * 16)) ^ ((lrow & 7) << 4));
            short8 afr = *(const short8*)(smem + off);
            #pragma unroll
            for (int nt = 0; nt < 4; ++nt)
                acc[nt] = __builtin_amdgcn_mfma_f32_16x16x32_bf16(afr, bfr[t * 4 + nt], acc[nt], 0, 0, 0);
        }

        // leaky(h1)+c1 -> wave-private scratch (bf16, XOR-swizzled rows)
        #pragma unroll
        for (int nt = 0; nt < 4; ++nt) {
            #pragma unroll
            for (int r = 0; r < 4; ++r) {
                float v = acc[nt][r] + c1v[nt];
                v = (v >= 0.f) ? v : a1v * v;
                int lr = lk * 4 + r;
                int colb = (nt * 16 + l15) * 2;
                *(ushort_t*)(h1b + lr * 128 + (colb ^ ((lr & 7) << 4))) = cvtbf(v);
            }
        }

        // layer 2+3 (wave-local; per-wave DS FIFO + data deps handle RAW/WAR)
        f32x4 acc2[2];
        acc2[0] = fz; acc2[1] = fz;
        #pragma unroll
        for (int kt = 0; kt < 2; ++kt) {
            short8 afr2 = *(const short8*)(h1b + l15 * 128 + ((kt * 64 + lk * 16) ^ ((l15 & 7) << 4)));
            #pragma unroll
            for (int nt = 0; nt < 2; ++nt)
                acc2[nt] = __builtin_amdgcn_mfma_f32_16x16x32_bf16(afr2, w2f[kt][nt], acc2[nt], 0, 0, 0);
        }
        #pragma unroll
        for (int r = 0; r < 4; ++r) {
            float sum = 0.f;
            #pragma unroll
            for (int nt = 0; nt < 2; ++nt) {
                float v = acc2[nt][r] + b2v[nt];
                v = (v >= 0.f) ? v : a2v * v;
                sum += v * w3v[nt];
            }
            sum += __shfl_xor(sum, 1);
            sum += __shfl_xor(sum, 2);
            sum += __shfl_xor(sum, 4);
            sum += __shfl_xor(sum, 8);
            if (l15 == 0) {
                int sg = rbase + mi * 16 + lk * 4 + r;
                if (sg < Ssz) {
                    float tw = __expf(0.1f * (float)(sg - (Ssz - 1)));
                    float sc = (sum + b3v) * tw;
                    scores_ws[bb * 800 + w * 200 + sg] =
                        kmask[bb * Ssz + sg] ? sc : -1.0e9f;
                }
            }
        }
    }
}

__device__ __forceinline__ void stage_keys_c1(char* smem, const float* keys,
                                              const float* c1ws, int bb, int half, int tid) {
    const float* kb = keys + (size_t)bb * Ssz * Dsz;
    const int rbase = half * 112;
    #pragma unroll 2
    for (int it = 0; it < 14; ++it) {          // 112 rows * 32 float4/row = 3584
        int id = tid + 256 * it;
        int row = id >> 5, c4 = id & 31;
        int grow = rbase + row;
        float4 kv = {0.f, 0.f, 0.f, 0.f};
        if (grow < Ssz) kv = *(const float4*)(kb + (size_t)grow * Dsz + c4 * 4);
        uint2 p;
        p.x = (uint_t)cvtbf(kv.x) | ((uint_t)cvtbf(kv.y) << 16);
        p.y = (uint_t)cvtbf(kv.z) | ((uint_t)cvtbf(kv.w) << 16);
        int off = KEYS_OFF + (((row << 8) + (c4 << 3)) ^ ((row & 7) << 4));
        *(uint2*)(smem + off) = p;
    }
    ((float*)(smem + C1S_OFF))[tid] = c1ws[bb * 256 + tid];
}

// ---------- kernel A (main path): bfr loaded from prefolded W1g2 ----------
__launch_bounds__(256, 3)
__global__ void scores_w1g(const float* __restrict__ keys, const int* __restrict__ kmask,
                           const float* __restrict__ a1, const float* __restrict__ b2,
                           const float* __restrict__ a2, const float* __restrict__ W3,
                           const float* __restrict__ b3,
                           const ushort_t* __restrict__ W2bf, const float* __restrict__ c1ws,
                           const ushort_t* __restrict__ W1g2, float* __restrict__ scores_ws) {
    extern __shared__ char smem[];
    const int tid  = threadIdx.x;
    const int bb   = blockIdx.x >> 1;
    const int half = blockIdx.x & 1;
    const int w   = tid >> 6;
    const int l15 = tid & 15;
    const int lk  = (tid & 63) >> 4;

    stage_keys_c1(smem, keys, c1ws, bb, half, tid);
    __builtin_amdgcn_sched_barrier(0);   // keep stage loads out of the fragment-load window

    // fragment loads land directly in bfr registers (coalesced 16B/lane)
    short8 bfr[16];
    const ushort_t* w1p = W1g2 + ((size_t)bb << 15);
    #pragma unroll
    for (int t = 0; t < 4; ++t)
        #pragma unroll
        for (int nt = 0; nt < 4; ++nt)
            bfr[t * 4 + nt] = *(const short8*)(w1p +
                (size_t)((t * 4 + lk) * 256 + w * 64 + nt * 16 + l15) * 8);

    scores_body(smem, bfr, kmask, a1, b2, a2, W3, b3, W2bf, c1ws, scores_ws,
                bb, half, w, l15, lk);
}

// ---------- kernel A (fallback, small ws): in-register fold at safe (256,2) ----------
__launch_bounds__(256, 2)
__global__ void scores_fold(const float* __restrict__ query, const float* __restrict__ keys,
                            const int* __restrict__ kmask,
                            const float* __restrict__ a1, const float* __restrict__ b2,
                            const float* __restrict__ a2, const float* __restrict__ W3,
                            const float* __restrict__ b3,
                            const float* __restrict__ W1sum, const float* __restrict__ W1c,
                            const ushort_t* __restrict__ W2bf, const float* __restrict__ c1ws,
                            float* __restrict__ scores_ws) {
    extern __shared__ char smem[];
    const int tid  = threadIdx.x;
    const int bb   = blockIdx.x >> 1;
    const int half = blockIdx.x & 1;
    const int w   = tid >> 6;
    const int l15 = tid & 15;
    const int lk  = (tid & 63) >> 4;

    stage_keys_c1(smem, keys, c1ws, bb, half, tid);
    __builtin_amdgcn_sched_barrier(0);

    short8 bfr[16];
    #pragma unroll
    for (int t = 0; t < 4; ++t) {
        const int k0 = t * 32 + lk * 8;
        const float4* pq = (const float4*)(query + bb * 128 + k0);
        float4 q0 = pq[0], q1 = pq[1];
        #pragma unroll
        for (int nt = 0; nt < 4; ++nt) {
            int n = w * 64 + nt * 16 + l15;
            const float4* ps = (const float4*)(W1sum + n * 128 + k0);
            const float4* pc = (const float4*)(W1c + n * 128 + k0);
            float4 s0 = ps[0], s1 = ps[1];
            float4 c0 = pc[0], c1f = pc[1];
            short8 ov;
            ov[0] = (short)cvtbf(s0.x + c0.x * q0.x);
            ov[1] = (short)cvtbf(s0.y + c0.y * q0.y);
            ov[2] = (short)cvtbf(s0.z + c0.z * q0.z);
            ov[3] = (short)cvtbf(s0.w + c0.w * q0.w);
            ov[4] = (short)cvtbf(s1.x + c1f.x * q1.x);
            ov[5] = (short)cvtbf(s1.y + c1f.y * q1.y);
            ov[6] = (short)cvtbf(s1.z + c1f.z * q1.z);
            ov[7] = (short)cvtbf(s1.w + c1f.w * q1.w);
            bfr[t * 4 + nt] = ov;
        }
    }

    scores_body(smem, bfr, kmask, a1, b2, a2, W3, b3, W2bf, c1ws, scores_ws,
                bb, half, w, l15, lk);
}

// ---------- kernel B: softmax -> avgw -> PV (avgw @ keys) -> projection ----------
__launch_bounds__(512, 4)
__global__ void finish_kernel(const float* __restrict__ keys, const float* __restrict__ WoT,
                              const float* __restrict__ bo, const float* __restrict__ scores_ws,
                              float* __restrict__ out) {
    __shared__ float scw[4][224];
    __shared__ float avgs[224];
    __shared__ float po[4][128];
    __shared__ float comb[128];
    __shared__ float po2[4][128];

    const int tid = threadIdx.x;
    const int bb  = blockIdx.x;
    const int w   = tid >> 6;
    const int l   = tid & 63;
    const float* kb = keys + (size_t)bb * Ssz * Dsz;

    // softmax per head on waves 0-3
    if (w < 4) {
        float xv[4], wv[4];
        float mx = -3.0e38f;
        #pragma unroll
        for (int i = 0; i < 4; ++i) {
            int s = l + 64 * i;
            xv[i] = (s < Ssz) ? scores_ws[bb * 800 + w * 200 + s] : -1.0e30f;
            mx = fmaxf(mx, xv[i]);
        }
        #pragma unroll
        for (int m = 1; m < 64; m <<= 1) mx = fmaxf(mx, __shfl_xor(mx, m));
        float sm = 0.f;
        #pragma unroll
        for (int i = 0; i < 4; ++i) {
            int s = l + 64 * i;
            wv[i] = (s < Ssz) ? __expf(xv[i] - mx) : 0.f;
            sm += wv[i];
        }
        #pragma unroll
        for (int m = 1; m < 64; m <<= 1) sm += __shfl_xor(sm, m);
        float inv = 1.0f / sm;
        #pragma unroll
        for (int i = 0; i < 4; ++i) {
            int s = l + 64 * i;
            if (s < Ssz) scw[w][s] = wv[i] * inv;
        }
    }
    __syncthreads();

    // avgw = mean over heads; also the avg_weights output
    if (tid < Ssz) {
        float aw = 0.25f * (scw[0][tid] + scw[1][tid] + scw[2][tid] + scw[3][tid]);
        avgs[tid] = aw;
        out[Bsz * Dsz + bb * Ssz + tid] = aw;
    }
    __syncthreads();

    // PV: combined[d] = sum_s avgw[s] * keys[s][d]; thread (d, quarter p)
    {
        int d = tid & 127, p = tid >> 7;
        float s0 = 0.f;
        for (int s = p; s < Ssz; s += 4)
            s0 += avgs[s] * kb[(size_t)s * Dsz + d];
        po[p][d] = s0;
    }
    __syncthreads();
    if (tid < 128) comb[tid] = po[0][tid] + po[1][tid] + po[2][tid] + po[3][tid];
    __syncthreads();

    // projection: 4 parts of 32 j each
    {
        int d = tid & 127, part = tid >> 7;
        float o = 0.f;
        const float* wp = WoT + (size_t)part * 32 * 128 + d;
        #pragma unroll 8
        for (int j = 0; j < 32; ++j) o += comb[part * 32 + j] * wp[j * 128];
        po2[part][d] = o;
    }
    __syncthreads();
    if (tid < 128) {
        out[bb * Dsz + tid] = bo[tid] + po2[0][tid] + po2[1][tid] + po2[2][tid] + po2[3][tid];
    }
}

// ws layout (bytes):
//   0        W1sum   131072
//   131072   W1c     131072
//   262144   W1diffR 131072
//   393216   WoT      65536
//   458752   W2bf     16384
//   475136   c1     2097152
//   2572288  scores 6553600
//   9125888  W1g2 134217728   => total 143,343,616 (guarded)
extern "C" void kernel_launch(void* const* d_in, const int* in_sizes, int n_in,
                              void* d_out, int out_size, void* d_ws, size_t ws_size,
                              hipStream_t stream) {
    const float* query = (const float*)d_in[0];
    const float* keys  = (const float*)d_in[1];
    const int*   kmask = (const int*)d_in[2];
    const float* W1    = (const float*)d_in[3];
    const float* b1    = (const float*)d_in[4];
    const float* a1    = (const float*)d_in[5];
    const float* W2    = (const float*)d_in[6];
    const float* b2    = (const float*)d_in[7];
    const float* a2    = (const float*)d_in[8];
    const float* W3    = (const float*)d_in[9];
    const float* b3    = (const float*)d_in[10];
    const float* Wo    = (const float*)d_in[11];
    const float* bo    = (const float*)d_in[12];
    float* out = (float*)d_out;

    char* ws = (char*)d_ws;
    float*    W1sum   = (float*)(ws);
    float*    W1c     = (float*)(ws + 131072);
    float*    W1diffR = (float*)(ws + 262144);
    float*    WoT     = (float*)(ws + 393216);
    ushort_t* W2bf    = (ushort_t*)(ws + 458752);
    float*    c1ws    = (float*)(ws + 475136);
    float*    scores  = (float*)(ws + 2572288);
    ushort_t* W1g2    = (ushort_t*)(ws + 9125888);

    const bool useW1G = ws_size >= (size_t)9125888 + (size_t)Bsz * 32768 * 2;

    prep_kernel<<<128, 256, 0, stream>>>(W1, W2, Wo, W1sum, W1c, W1diffR, WoT, W2bf);

    if (useW1G) {
        hipFuncSetAttribute(reinterpret_cast<const void*>(scores_w1g),
                            hipFuncAttributeMaxDynamicSharedMemorySize, SMEM_A);
        w1effc1_kernel<<<Bsz, 256, 0, stream>>>(query, W1sum, W1c, W1diffR, b1, W1g2, c1ws);
        scores_w1g<<<Bsz * 2, 256, SMEM_A, stream>>>(keys, kmask, a1, b2, a2, W3, b3,
                                                     W2bf, c1ws, W1g2, scores);
    } else {
        hipFuncSetAttribute(reinterpret_cast<const void*>(scores_fold),
                            hipFuncAttributeMaxDynamicSharedMemorySize, SMEM_A);
        c1_kernel<<<Bsz, 256, 0, stream>>>(query, W1diffR, b1, c1ws);
        scores_fold<<<Bsz * 2, 256, SMEM_A, stream>>>(query, keys, kmask, a1, b2, a2, W3, b3,
                                                      W1sum, W1c, W2bf, c1ws, scores);
    }
    finish_kernel<<<Bsz, 512, 0, stream>>>(keys, WoT, bo, scores, out);
}

// Round 14
// 244.704 us; speedup vs baseline: 1.2786x; 1.2786x over previous
//
#include <hip/hip_runtime.h>
#include <hip/hip_bf16.h>
#include <stdint.h>

// Problem constants
#define Bsz 2048
#define Ssz 200
#define Dsz 128

typedef __attribute__((ext_vector_type(8))) short short8;
typedef __attribute__((ext_vector_type(4))) short short4v;
typedef __attribute__((ext_vector_type(4))) float f32x4;
typedef unsigned short ushort_t;
typedef unsigned int uint_t;

// ---- scores kernel LDS (total 30,720) ----
#define KEYS_OFF   0        // [112][128] bf16, XOR-swizzled  28,672
#define SCB_OFF    28672    // [4 waves][128] f32 (112 used)   2,048
#define SMEM_A     30720

#if defined(__has_builtin)
#if __has_builtin(__builtin_amdgcn_mfma_f32_16x16x16bf16_1k)
#define HAVE_MFMA16 1
#endif
#endif

__device__ __forceinline__ f32x4 mfma16(short4v a, short4v b, f32x4 c) {
#ifdef HAVE_MFMA16
    return __builtin_amdgcn_mfma_f32_16x16x16bf16_1k(a, b, c, 0, 0, 0);
#else
    f32x4 d;
    asm volatile("v_mfma_f32_16x16x16_bf16 %0, %1, %2, %3"
                 : "=&v"(d) : "v"(a), "v"(b), "v"(c));   // early-clobber: d must not alias a/b
    return d;
#endif
}

__device__ __forceinline__ ushort_t cvtbf(float x) {
    __hip_bfloat16 h = __float2bfloat16(x);   // RTNE; pairs into v_cvt_pk_bf16_f32
    ushort_t u;
    __builtin_memcpy(&u, &h, 2);
    return u;
}
__device__ __forceinline__ float bflo(uint_t kv) {
    union { uint_t u; float f; } v; v.u = kv << 16; return v.f;
}
__device__ __forceinline__ float bfhi(uint_t kv) {
    union { uint_t u; float f; } v; v.u = kv & 0xFFFF0000u; return v.f;
}

// ---------- prep: fold W1 (sum/c/diff row-major), transpose Wo, cast W2 ----------
__global__ void prep_kernel(const float* __restrict__ W1, const float* __restrict__ W2,
                            const float* __restrict__ Wo,
                            float* __restrict__ W1sum, float* __restrict__ W1c,
                            float* __restrict__ W1diffR, float* __restrict__ WoT,
                            ushort_t* __restrict__ W2bf) {
    int i = blockIdx.x * blockDim.x + threadIdx.x;
    if (i < 32768) {                       // n in [0,256), j in [0,128)
        int n = i >> 7, j = i & 127;
        float a  = W1[n * 512 + j];        // keys part
        float dd = W1[n * 512 + 384 + j];  // (k - q) part
        W1sum[i] = a + dd;                 // coeff of k
        W1c[i]   = W1[n * 512 + 256 + j];  // coeff of k*q
        W1diffR[i] = W1[n * 512 + 128 + j] - dd;  // coeff of q (row-major)
    }
    if (i < 16384) {                       // WoT[j][d] = Wo[d][j]
        int j = i >> 7, d = i & 127;
        WoT[i] = Wo[d * 128 + j];
    }
    if (i < 8192) W2bf[i] = cvtbf(W2[i]); // flat [h][e][k], k fastest
}

// ---------- per-b: c1 bias + folded layer-1 weight in MFMA-fragment order ----------
__global__ void w1effc1_kernel(const float* __restrict__ query, const float* __restrict__ W1sum,
                               const float* __restrict__ W1c, const float* __restrict__ W1diffR,
                               const float* __restrict__ b1,
                               ushort_t* __restrict__ W1g2, float* __restrict__ c1out) {
    __shared__ float qs[128];
    int b = blockIdx.x, t = threadIdx.x;
    if (t < 128) qs[t] = query[b * 128 + t];
    __syncthreads();
    {
        float acc = b1[t];
        const float4* wr  = (const float4*)(W1diffR + t * 128);
        const float4* qv4 = (const float4*)qs;
        #pragma unroll 8
        for (int j4 = 0; j4 < 32; ++j4) {
            float4 wv = wr[j4];
            float4 qq = qv4[j4];
            acc += wv.x * qq.x + wv.y * qq.y + wv.z * qq.z + wv.w * qq.w;
        }
        c1out[b * 256 + t] = acc;
    }
    ushort_t* wout = W1g2 + ((size_t)b << 15);
    #pragma unroll 2
    for (int it = 0; it < 16; ++it) {
        int o  = t + 256 * it;
        int t4 = o >> 10, lk = (o >> 8) & 3, n = o & 255;
        int k0 = t4 * 32 + lk * 8;
        const float4* ps = (const float4*)(W1sum + n * 128 + k0);
        const float4* pc = (const float4*)(W1c + n * 128 + k0);
        const float4* pq = (const float4*)(qs + k0);
        float4 s0 = ps[0], s1 = ps[1];
        float4 c0 = pc[0], c1f = pc[1];
        float4 q0 = pq[0], q1 = pq[1];
        short8 ov;
        ov[0] = (short)cvtbf(s0.x + c0.x * q0.x);
        ov[1] = (short)cvtbf(s0.y + c0.y * q0.y);
        ov[2] = (short)cvtbf(s0.z + c0.z * q0.z);
        ov[3] = (short)cvtbf(s0.w + c0.w * q0.w);
        ov[4] = (short)cvtbf(s1.x + c1f.x * q1.x);
        ov[5] = (short)cvtbf(s1.y + c1f.y * q1.y);
        ov[6] = (short)cvtbf(s1.z + c1f.z * q1.z);
        ov[7] = (short)cvtbf(s1.w + c1f.w * q1.w);
        *(short8*)(wout + (size_t)o * 8) = ov;
    }
}

// ---------- per-b bias only (fallback path) ----------
__global__ void c1_kernel(const float* __restrict__ query, const float* __restrict__ W1diffR,
                          const float* __restrict__ b1, float* __restrict__ c1out) {
    int b = blockIdx.x, n = threadIdx.x;
    float acc = b1[n];
    const float4* wr  = (const float4*)(W1diffR + n * 128);
    const float4* qv4 = (const float4*)(query + b * 128);
    #pragma unroll 8
    for (int j4 = 0; j4 < 32; ++j4) {
        float4 wv = wr[j4];
        float4 qq = qv4[j4];
        acc += wv.x * qq.x + wv.y * qq.y + wv.z * qq.z + wv.w * qq.w;
    }
    c1out[b * 256 + n] = acc;
}

__device__ __forceinline__ void stage_keys(char* smem, const float* keys,
                                           int bb, int half, int tid) {
    const float* kb = keys + (size_t)bb * Ssz * Dsz;
    const int rbase = half * 112;
    #pragma unroll 2
    for (int it = 0; it < 14; ++it) {          // 112 rows * 32 float4/row = 3584
        int id = tid + 256 * it;
        int row = id >> 5, c4 = id & 31;
        int grow = rbase + row;
        float4 kv = {0.f, 0.f, 0.f, 0.f};
        if (grow < Ssz) kv = *(const float4*)(kb + (size_t)grow * Dsz + c4 * 4);
        uint2 p;
        p.x = (uint_t)cvtbf(kv.x) | ((uint_t)cvtbf(kv.y) << 16);
        p.y = (uint_t)cvtbf(kv.z) | ((uint_t)cvtbf(kv.w) << 16);
        int off = KEYS_OFF + (((row << 8) + (c4 << 3)) ^ ((row & 7) << 4));
        *(uint2*)(smem + off) = p;
    }
}

// ========== shared score-pipeline body (swapped-MFMA; h1 stays in registers) ==========
__device__ __forceinline__ void scores_body(char* smem, const short8* bfr,
                                            const int* kmask,
                                            const float* a1, const float* b2,
                                            const float* a2, const float* W3,
                                            const float* b3, const ushort_t* W2bf,
                                            const float* c1ws, float* scores_ws,
                                            float* numws, float* mdws,
                                            int bb, int half, int w, int l, int l15, int lk) {
    const int rbase = half * 112;

    const float a1v = a1[w];
    const float a2v = a2[w];
    const float b3v = b3[w];
    float c1v[4][4], b2v[2][4], w3v[2][4];
    #pragma unroll
    for (int kt = 0; kt < 4; ++kt)
        #pragma unroll
        for (int r = 0; r < 4; ++r)
            c1v[kt][r] = c1ws[bb * 256 + w * 64 + kt * 16 + lk * 4 + r];
    #pragma unroll
    for (int nt2 = 0; nt2 < 2; ++nt2)
        #pragma unroll
        for (int r = 0; r < 4; ++r) {
            b2v[nt2][r] = b2[w * 32 + nt2 * 16 + lk * 4 + r];
            w3v[nt2][r] = W3[w * 32 + nt2 * 16 + lk * 4 + r];
        }
    // W2 A-frags for 16x16x16: lane holds W2[e=nt2*16+l15][n=kt*16+lk*4 .. +4]
    short4v w2a[2][4];
    #pragma unroll
    for (int nt2 = 0; nt2 < 2; ++nt2)
        #pragma unroll
        for (int kt = 0; kt < 4; ++kt)
            w2a[nt2][kt] = *(const short4v*)(W2bf + w * 2048 + (nt2 * 16 + l15) * 64
                                             + kt * 16 + lk * 4);

    __syncthreads();   // keys staged

    const f32x4 fz = {0.f, 0.f, 0.f, 0.f};
    float* scb = (float*)(smem + SCB_OFF + w * 512);   // wave-private scores (112 used)
    const int ntiles = 7 - half;

    #pragma unroll 1
    for (int mi = 0; mi < ntiles; ++mi) {
        // layer 1 (swapped): acc[kt] = h1^T tile: row = n_local(lk*4+r), col = s(l15)
        f32x4 acc[4];
        #pragma unroll
        for (int kt = 0; kt < 4; ++kt) acc[kt] = fz;
        #pragma unroll
        for (int t = 0; t < 4; ++t) {
            int lrow = mi * 16 + l15;
            int off = KEYS_OFF + (((lrow << 8) + (t * 64 + lk * 16)) ^ ((lrow & 7) << 4));
            short8 kfr = *(const short8*)(smem + off);
            #pragma unroll
            for (int kt = 0; kt < 4; ++kt)
                acc[kt] = __builtin_amdgcn_mfma_f32_16x16x32_bf16(bfr[t * 4 + kt], kfr, acc[kt], 0, 0, 0);
        }
        // leaky + pack: pa[kt] = bf16x4 of h1[n=kt*16+lk*4+j][s=l15]
        short4v pa[4];
        #pragma unroll
        for (int kt = 0; kt < 4; ++kt) {
            #pragma unroll
            for (int r = 0; r < 4; ++r) {
                float v = acc[kt][r] + c1v[kt][r];
                v = (v >= 0.f) ? v : a1v * v;
                pa[kt][r] = (short)cvtbf(v);
            }
        }
        // layer 2: acc2[nt2] = h2^T: row = e_local(lk*4+r), col = s(l15)
        f32x4 acc2[2];
        acc2[0] = fz; acc2[1] = fz;
        #pragma unroll
        for (int kt = 0; kt < 4; ++kt) {
            acc2[0] = mfma16(w2a[0][kt], pa[kt], acc2[0]);
            acc2[1] = mfma16(w2a[1][kt], pa[kt], acc2[1]);
        }
        // layer 3: each lane sums its 8 e-values for s = l15; reduce over lk groups
        float sum = 0.f;
        #pragma unroll
        for (int nt2 = 0; nt2 < 2; ++nt2) {
            #pragma unroll
            for (int r = 0; r < 4; ++r) {
                float v = acc2[nt2][r] + b2v[nt2][r];
                v = (v >= 0.f) ? v : a2v * v;
                sum += v * w3v[nt2][r];
            }
        }
        sum += __shfl_xor(sum, 16);
        sum += __shfl_xor(sum, 32);
        // lanes 0..15 hold score for s = rbase + mi*16 + l15
        if (l < 16) {
            int sl = mi * 16 + l15;
            int sg = rbase + sl;
            if (sg < Ssz) {
                float tw = __expf(0.1f * (float)(sg - (Ssz - 1)));
                float sc = (sum + b3v) * tw;
                sc = kmask[bb * Ssz + sg] ? sc : -1.0e9f;
                scores_ws[bb * 800 + w * 200 + sg] = sc;
                scb[sl] = sc;
            } else {
                scb[sl] = -1.0e30f;
            }
        }
    }

    // ---- wave-local partial softmax + PV over this half's rows ----
    {
        int s0i = l, s1i = l + 64;
        bool v0 = (rbase + s0i < Ssz);
        bool v1 = (s1i < 112) && (rbase + s1i < Ssz);
        float x0 = v0 ? scb[s0i] : -1.0e30f;
        float x1 = v1 ? scb[s1i] : -1.0e30f;
        float m = fmaxf(x0, x1);
        #pragma unroll
        for (int mm = 1; mm < 64; mm <<= 1) m = fmaxf(m, __shfl_xor(m, mm));
        float e0 = v0 ? __expf(x0 - m) : 0.f;
        float e1 = v1 ? __expf(x1 - m) : 0.f;
        float dsum = e0 + e1;
        #pragma unroll
        for (int mm = 1; mm < 64; mm <<= 1) dsum += __shfl_xor(dsum, mm);
        scb[s0i] = e0;
        if (s1i < 112) scb[s1i] = e1;
        // PV: lane covers d = 2l, 2l+1; keys bf16 from LDS
        float n0 = 0.f, n1 = 0.f;
        #pragma unroll 4
        for (int s = 0; s < 112; ++s) {
            float wv = scb[s];
            uint_t kv = *(const uint_t*)(smem + KEYS_OFF + (((s << 8) + 4 * l) ^ ((s & 7) << 4)));
            n0 += wv * bflo(kv);
            n1 += wv * bfhi(kv);
        }
        size_t base = ((size_t)(bb * 4 + w) * 2 + half) * 128;   // numws: 16384 x 128 f32 = 8 MB
        numws[base + 2 * l]     = n0;
        numws[base + 2 * l + 1] = n1;
        if (l == 0) {
            mdws[((bb * 4 + w) * 2 + half) * 2]     = m;
            mdws[((bb * 4 + w) * 2 + half) * 2 + 1] = dsum;
        }
    }
}

// ---------- kernel A (main path): bfr loaded from prefolded W1g2 ----------
__launch_bounds__(256, 3)
__global__ void scores_w1g(const float* __restrict__ keys, const int* __restrict__ kmask,
                           const float* __restrict__ a1, const float* __restrict__ b2,
                           const float* __restrict__ a2, const float* __restrict__ W3,
                           const float* __restrict__ b3,
                           const ushort_t* __restrict__ W2bf, const float* __restrict__ c1ws,
                           const ushort_t* __restrict__ W1g2, float* __restrict__ scores_ws,
                           float* __restrict__ numws, float* __restrict__ mdws) {
    extern __shared__ char smem[];
    const int tid  = threadIdx.x;
    const int bb   = blockIdx.x >> 1;
    const int half = blockIdx.x & 1;
    const int w   = tid >> 6;
    const int l   = tid & 63;
    const int l15 = l & 15;
    const int lk  = l >> 4;

    stage_keys(smem, keys, bb, half, tid);
    __builtin_amdgcn_sched_barrier(0);

    short8 bfr[16];
    const ushort_t* w1p = W1g2 + ((size_t)bb << 15);
    #pragma unroll
    for (int t = 0; t < 4; ++t)
        #pragma unroll
        for (int nt = 0; nt < 4; ++nt)
            bfr[t * 4 + nt] = *(const short8*)(w1p +
                (size_t)((t * 4 + lk) * 256 + w * 64 + nt * 16 + l15) * 8);

    scores_body(smem, bfr, kmask, a1, b2, a2, W3, b3, W2bf, c1ws, scores_ws,
                numws, mdws, bb, half, w, l, l15, lk);
}

// ---------- kernel A (fallback, small ws): in-register fold at safe (256,2) ----------
__launch_bounds__(256, 2)
__global__ void scores_fold(const float* __restrict__ query, const float* __restrict__ keys,
                            const int* __restrict__ kmask,
                            const float* __restrict__ a1, const float* __restrict__ b2,
                            const float* __restrict__ a2, const float* __restrict__ W3,
                            const float* __restrict__ b3,
                            const float* __restrict__ W1sum, const float* __restrict__ W1c,
                            const ushort_t* __restrict__ W2bf, const float* __restrict__ c1ws,
                            float* __restrict__ scores_ws,
                            float* __restrict__ numws, float* __restrict__ mdws) {
    extern __shared__ char smem[];
    const int tid  = threadIdx.x;
    const int bb   = blockIdx.x >> 1;
    const int half = blockIdx.x & 1;
    const int w   = tid >> 6;
    const int l   = tid & 63;
    const int l15 = l & 15;
    const int lk  = l >> 4;

    stage_keys(smem, keys, bb, half, tid);
    __builtin_amdgcn_sched_barrier(0);

    short8 bfr[16];
    #pragma unroll
    for (int t = 0; t < 4; ++t) {
        const int k0 = t * 32 + lk * 8;
        const float4* pq = (const float4*)(query + bb * 128 + k0);
        float4 q0 = pq[0], q1 = pq[1];
        #pragma unroll
        for (int nt = 0; nt < 4; ++nt) {
            int n = w * 64 + nt * 16 + l15;
            const float4* ps = (const float4*)(W1sum + n * 128 + k0);
            const float4* pc = (const float4*)(W1c + n * 128 + k0);
            float4 s0 = ps[0], s1 = ps[1];
            float4 c0 = pc[0], c1f = pc[1];
            short8 ov;
            ov[0] = (short)cvtbf(s0.x + c0.x * q0.x);
            ov[1] = (short)cvtbf(s0.y + c0.y * q0.y);
            ov[2] = (short)cvtbf(s0.z + c0.z * q0.z);
            ov[3] = (short)cvtbf(s0.w + c0.w * q0.w);
            ov[4] = (short)cvtbf(s1.x + c1f.x * q1.x);
            ov[5] = (short)cvtbf(s1.y + c1f.y * q1.y);
            ov[6] = (short)cvtbf(s1.z + c1f.z * q1.z);
            ov[7] = (short)cvtbf(s1.w + c1f.w * q1.w);
            bfr[t * 4 + nt] = ov;
        }
    }

    scores_body(smem, bfr, kmask, a1, b2, a2, W3, b3, W2bf, c1ws, scores_ws,
                numws, mdws, bb, half, w, l, l15, lk);
}

// ---------- kernel B: softmax (avg out) + half-combine PV + projection ----------
__launch_bounds__(256, 4)
__global__ void finish_comb(const float* __restrict__ scores_ws, const float* __restrict__ numws,
                            const float* __restrict__ mdws, const float* __restrict__ WoT,
                            const float* __restrict__ bo, float* __restrict__ out) {
    __shared__ float scw[4][224];
    __shared__ float comb[128];
    __shared__ float po2[2][128];

    const int tid = threadIdx.x;
    const int bb  = blockIdx.x;
    const int w   = tid >> 6;
    const int l   = tid & 63;

    // softmax per head (for avg_weights output only)
    {
        float xv[4], wv[4];
        float mx = -3.0e38f;
        #pragma unroll
        for (int i = 0; i < 4; ++i) {
            int s = l + 64 * i;
            xv[i] = (s < Ssz) ? scores_ws[bb * 800 + w * 200 + s] : -1.0e30f;
            mx = fmaxf(mx, xv[i]);
        }
        #pragma unroll
        for (int m = 1; m < 64; m <<= 1) mx = fmaxf(mx, __shfl_xor(mx, m));
        float sm = 0.f;
        #pragma unroll
        for (int i = 0; i < 4; ++i) {
            int s = l + 64 * i;
            wv[i] = (s < Ssz) ? __expf(xv[i] - mx) : 0.f;
            sm += wv[i];
        }
        #pragma unroll
        for (int m = 1; m < 64; m <<= 1) sm += __shfl_xor(sm, m);
        float inv = 1.0f / sm;
        #pragma unroll
        for (int i = 0; i < 4; ++i) {
            int s = l + 64 * i;
            if (s < Ssz) scw[w][s] = wv[i] * inv;
        }
    }
    __syncthreads();

    if (tid < Ssz) {
        float aw = 0.25f * (scw[0][tid] + scw[1][tid] + scw[2][tid] + scw[3][tid]);
        out[Bsz * Dsz + bb * Ssz + tid] = aw;
    }

    // combine per-half PV partials: comb[d] = mean_h (num0*a0 + num1*a1)/den
    if (tid < 128) {
        float c = 0.f;
        #pragma unroll
        for (int h = 0; h < 4; ++h) {
            int mb = ((bb * 4 + h) * 2) * 2;
            float m0 = mdws[mb], d0 = mdws[mb + 1];
            float m1 = mdws[mb + 2], d1 = mdws[mb + 3];
            float m = fmaxf(m0, m1);
            float a0 = __expf(m0 - m), a1 = __expf(m1 - m);
            float den = d0 * a0 + d1 * a1;
            size_t nb = (size_t)((bb * 4 + h) * 2) * 128;
            c += (numws[nb + tid] * a0 + numws[nb + 128 + tid] * a1) / den;
        }
        comb[tid] = 0.25f * c;
    }
    __syncthreads();

    // projection: 2 parts of 64 j each
    {
        int d = tid & 127, part = tid >> 7;
        float o = 0.f;
        const float* wp = WoT + (size_t)part * 64 * 128 + d;
        #pragma unroll 8
        for (int j = 0; j < 64; ++j) o += comb[part * 64 + j] * wp[j * 128];
        po2[part][d] = o;
    }
    __syncthreads();
    if (tid < 128) out[bb * Dsz + tid] = bo[tid] + po2[0][tid] + po2[1][tid];
}

// ws layout (bytes) — R13 BUG WAS HERE: numws needs 16384*128*4 = 8,388,608 (had 4 MB;
// overflow clobbered mdws + the first 4 MB of W1g2 -> garbage weights).
//   0         W1sum   131072
//   131072    W1c     131072
//   262144    W1diffR 131072
//   393216    WoT      65536
//   458752    W2bf     16384
//   475136    c1     2097152
//   2572288   scores 6553600
//   9125888   numws  8388608
//   17514496  mdws    131072
//   17645568  W1g2 134217728   => total 151,863,296 (guarded)
extern "C" void kernel_launch(void* const* d_in, const int* in_sizes, int n_in,
                              void* d_out, int out_size, void* d_ws, size_t ws_size,
                              hipStream_t stream) {
    const float* query = (const float*)d_in[0];
    const float* keys  = (const float*)d_in[1];
    const int*   kmask = (const int*)d_in[2];
    const float* W1    = (const float*)d_in[3];
    const float* b1    = (const float*)d_in[4];
    const float* a1    = (const float*)d_in[5];
    const float* W2    = (const float*)d_in[6];
    const float* b2    = (const float*)d_in[7];
    const float* a2    = (const float*)d_in[8];
    const float* W3    = (const float*)d_in[9];
    const float* b3    = (const float*)d_in[10];
    const float* Wo    = (const float*)d_in[11];
    const float* bo    = (const float*)d_in[12];
    float* out = (float*)d_out;

    char* ws = (char*)d_ws;
    float*    W1sum   = (float*)(ws);
    float*    W1c     = (float*)(ws + 131072);
    float*    W1diffR = (float*)(ws + 262144);
    float*    WoT     = (float*)(ws + 393216);
    ushort_t* W2bf    = (ushort_t*)(ws + 458752);
    float*    c1ws    = (float*)(ws + 475136);
    float*    scores  = (float*)(ws + 2572288);
    float*    numws   = (float*)(ws + 9125888);
    float*    mdws    = (float*)(ws + 17514496);
    ushort_t* W1g2    = (ushort_t*)(ws + 17645568);

    const bool useW1G = ws_size >= (size_t)17645568 + (size_t)Bsz * 32768 * 2;

    prep_kernel<<<128, 256, 0, stream>>>(W1, W2, Wo, W1sum, W1c, W1diffR, WoT, W2bf);

    if (useW1G) {
        hipFuncSetAttribute(reinterpret_cast<const void*>(scores_w1g),
                            hipFuncAttributeMaxDynamicSharedMemorySize, SMEM_A);
        w1effc1_kernel<<<Bsz, 256, 0, stream>>>(query, W1sum, W1c, W1diffR, b1, W1g2, c1ws);
        scores_w1g<<<Bsz * 2, 256, SMEM_A, stream>>>(keys, kmask, a1, b2, a2, W3, b3,
                                                     W2bf, c1ws, W1g2, scores, numws, mdws);
    } else {
        hipFuncSetAttribute(reinterpret_cast<const void*>(scores_fold),
                            hipFuncAttributeMaxDynamicSharedMemorySize, SMEM_A);
        c1_kernel<<<Bsz, 256, 0, stream>>>(query, W1diffR, b1, c1ws);
        scores_fold<<<Bsz * 2, 256, SMEM_A, stream>>>(query, keys, kmask, a1, b2, a2, W3, b3,
                                                      W1sum, W1c, W2bf, c1ws, scores,
                                                      numws, mdws);
    }
    finish_comb<<<Bsz, 256, 0, stream>>>(scores, numws, mdws, WoT, bo, out);
}

// Round 15
// 223.332 us; speedup vs baseline: 1.4009x; 1.0957x over previous
//
#include <hip/hip_runtime.h>
#include <hip/hip_bf16.h>
#include <stdint.h>

// Problem constants
#define Bsz 2048
#define Ssz 200
#define Dsz 128

typedef __attribute__((ext_vector_type(8))) short short8;
typedef __attribute__((ext_vector_type(4))) short short4v;
typedef __attribute__((ext_vector_type(4))) float f32x4;
typedef unsigned short ushort_t;
typedef unsigned int uint_t;

// ---- scores kernel LDS (total 32,768 -> 4 blocks/CU) ----
#define KEYS_OFF   0        // [112][128] bf16, XOR-swizzled  28,672
#define SCB_OFF    28672    // [4 waves][128] f32 (112 used)   2,048
#define C1S_OFF    30720    // [256] f32                       1,024
#define B2S_OFF    31744    // [128] f32                         512
#define W3S_OFF    32256    // [128] f32                         512
#define SMEM_A     32768

#if defined(__has_builtin)
#if __has_builtin(__builtin_amdgcn_mfma_f32_16x16x16bf16_1k)
#define HAVE_MFMA16 1
#endif
#endif

__device__ __forceinline__ f32x4 mfma16(short4v a, short4v b, f32x4 c) {
#ifdef HAVE_MFMA16
    return __builtin_amdgcn_mfma_f32_16x16x16bf16_1k(a, b, c, 0, 0, 0);
#else
    f32x4 d;
    asm volatile("v_mfma_f32_16x16x16_bf16 %0, %1, %2, %3"
                 : "=&v"(d) : "v"(a), "v"(b), "v"(c));
    return d;
#endif
}

__device__ __forceinline__ ushort_t cvtbf(float x) {
    __hip_bfloat16 h = __float2bfloat16(x);   // RTNE; pairs into v_cvt_pk_bf16_f32
    ushort_t u;
    __builtin_memcpy(&u, &h, 2);
    return u;
}
__device__ __forceinline__ float bflo(uint_t kv) {
    union { uint_t u; float f; } v; v.u = kv << 16; return v.f;
}
__device__ __forceinline__ float bfhi(uint_t kv) {
    union { uint_t u; float f; } v; v.u = kv & 0xFFFF0000u; return v.f;
}

// ---------- prep: fold W1 (sum/c/diff row-major), transpose Wo, cast W2 ----------
__global__ void prep_kernel(const float* __restrict__ W1, const float* __restrict__ W2,
                            const float* __restrict__ Wo,
                            float* __restrict__ W1sum, float* __restrict__ W1c,
                            float* __restrict__ W1diffR, float* __restrict__ WoT,
                            ushort_t* __restrict__ W2bf) {
    int i = blockIdx.x * blockDim.x + threadIdx.x;
    if (i < 32768) {                       // n in [0,256), j in [0,128)
        int n = i >> 7, j = i & 127;
        float a  = W1[n * 512 + j];        // keys part
        float dd = W1[n * 512 + 384 + j];  // (k - q) part
        W1sum[i] = a + dd;                 // coeff of k
        W1c[i]   = W1[n * 512 + 256 + j];  // coeff of k*q
        W1diffR[i] = W1[n * 512 + 128 + j] - dd;  // coeff of q (row-major)
    }
    if (i < 16384) {                       // WoT[j][d] = Wo[d][j]
        int j = i >> 7, d = i & 127;
        WoT[i] = Wo[d * 128 + j];
    }
    if (i < 8192) W2bf[i] = cvtbf(W2[i]); // flat [h][e][k], k fastest
}

// ---------- per-b: c1 bias + folded layer-1 weight in MFMA-fragment order ----------
__global__ void w1effc1_kernel(const float* __restrict__ query, const float* __restrict__ W1sum,
                               const float* __restrict__ W1c, const float* __restrict__ W1diffR,
                               const float* __restrict__ b1,
                               ushort_t* __restrict__ W1g2, float* __restrict__ c1out) {
    __shared__ float qs[128];
    int b = blockIdx.x, t = threadIdx.x;
    if (t < 128) qs[t] = query[b * 128 + t];
    __syncthreads();
    {
        float acc = b1[t];
        const float4* wr  = (const float4*)(W1diffR + t * 128);
        const float4* qv4 = (const float4*)qs;
        #pragma unroll 8
        for (int j4 = 0; j4 < 32; ++j4) {
            float4 wv = wr[j4];
            float4 qq = qv4[j4];
            acc += wv.x * qq.x + wv.y * qq.y + wv.z * qq.z + wv.w * qq.w;
        }
        c1out[b * 256 + t] = acc;
    }
    ushort_t* wout = W1g2 + ((size_t)b << 15);
    #pragma unroll 2
    for (int it = 0; it < 16; ++it) {
        int o  = t + 256 * it;
        int t4 = o >> 10, lk = (o >> 8) & 3, n = o & 255;
        int k0 = t4 * 32 + lk * 8;
        const float4* ps = (const float4*)(W1sum + n * 128 + k0);
        const float4* pc = (const float4*)(W1c + n * 128 + k0);
        const float4* pq = (const float4*)(qs + k0);
        float4 s0 = ps[0], s1 = ps[1];
        float4 c0 = pc[0], c1f = pc[1];
        float4 q0 = pq[0], q1 = pq[1];
        short8 ov;
        ov[0] = (short)cvtbf(s0.x + c0.x * q0.x);
        ov[1] = (short)cvtbf(s0.y + c0.y * q0.y);
        ov[2] = (short)cvtbf(s0.z + c0.z * q0.z);
        ov[3] = (short)cvtbf(s0.w + c0.w * q0.w);
        ov[4] = (short)cvtbf(s1.x + c1f.x * q1.x);
        ov[5] = (short)cvtbf(s1.y + c1f.y * q1.y);
        ov[6] = (short)cvtbf(s1.z + c1f.z * q1.z);
        ov[7] = (short)cvtbf(s1.w + c1f.w * q1.w);
        *(short8*)(wout + (size_t)o * 8) = ov;
    }
}

// ---------- per-b bias only (fallback path) ----------
__global__ void c1_kernel(const float* __restrict__ query, const float* __restrict__ W1diffR,
                          const float* __restrict__ b1, float* __restrict__ c1out) {
    int b = blockIdx.x, n = threadIdx.x;
    float acc = b1[n];
    const float4* wr  = (const float4*)(W1diffR + n * 128);
    const float4* qv4 = (const float4*)(query + b * 128);
    #pragma unroll 8
    for (int j4 = 0; j4 < 32; ++j4) {
        float4 wv = wr[j4];
        float4 qq = qv4[j4];
        acc += wv.x * qq.x + wv.y * qq.y + wv.z * qq.z + wv.w * qq.w;
    }
    c1out[b * 256 + n] = acc;
}

// stage keys + c1 + b2 + W3 into LDS
__device__ __forceinline__ void stage_all(char* smem, const float* keys,
                                          const float* c1ws, const float* b2g,
                                          const float* w3g, int bb, int half, int tid) {
    const float* kb = keys + (size_t)bb * Ssz * Dsz;
    const int rbase = half * 112;
    #pragma unroll 2
    for (int it = 0; it < 14; ++it) {          // 112 rows * 32 float4/row = 3584
        int id = tid + 256 * it;
        int row = id >> 5, c4 = id & 31;
        int grow = rbase + row;
        float4 kv = {0.f, 0.f, 0.f, 0.f};
        if (grow < Ssz) kv = *(const float4*)(kb + (size_t)grow * Dsz + c4 * 4);
        uint2 p;
        p.x = (uint_t)cvtbf(kv.x) | ((uint_t)cvtbf(kv.y) << 16);
        p.y = (uint_t)cvtbf(kv.z) | ((uint_t)cvtbf(kv.w) << 16);
        int off = KEYS_OFF + (((row << 8) + (c4 << 3)) ^ ((row & 7) << 4));
        *(uint2*)(smem + off) = p;
    }
    ((float*)(smem + C1S_OFF))[tid] = c1ws[bb * 256 + tid];
    if (tid < 128) ((float*)(smem + B2S_OFF))[tid] = b2g[tid];
    else if (tid < 256) ((float*)(smem + W3S_OFF))[tid - 128] = w3g[tid - 128];
}

// ========== shared score-pipeline body (swapped-MFMA; h1 stays in registers) ==========
__device__ __forceinline__ void scores_body(char* smem, const short8* bfr,
                                            const int* kmask,
                                            const float* a1, const float* a2,
                                            const float* b3, const ushort_t* W2bf,
                                            float* scores_ws,
                                            float* numws, float* mdws,
                                            int bb, int half, int w, int l, int l15, int lk) {
    const int rbase = half * 112;

    const float a1v = a1[w];
    const float a2v = a2[w];
    const float b3v = b3[w];
    // W2 A-frags for 16x16x16: lane holds W2[e=nt2*16+l15][n=kt*16+lk*4 .. +4]
    short4v w2a[2][4];
    #pragma unroll
    for (int nt2 = 0; nt2 < 2; ++nt2)
        #pragma unroll
        for (int kt = 0; kt < 4; ++kt)
            w2a[nt2][kt] = *(const short4v*)(W2bf + w * 2048 + (nt2 * 16 + l15) * 64
                                             + kt * 16 + lk * 4);

    __syncthreads();   // keys + c1 + b2 + W3 staged

    const f32x4 fz = {0.f, 0.f, 0.f, 0.f};
    float* scb = (float*)(smem + SCB_OFF + w * 512);   // wave-private scores (112 used)
    const float* c1s = (const float*)(smem + C1S_OFF);
    const float* b2s = (const float*)(smem + B2S_OFF);
    const float* w3s = (const float*)(smem + W3S_OFF);
    const int ntiles = 7 - half;

    #pragma unroll 1
    for (int mi = 0; mi < ntiles; ++mi) {
        // layer 1 (swapped): acc[kt] = h1^T tile: row = n_local(lk*4+r), col = s(l15)
        f32x4 acc[4];
        #pragma unroll
        for (int kt = 0; kt < 4; ++kt) acc[kt] = fz;
        #pragma unroll
        for (int t = 0; t < 4; ++t) {
            int lrow = mi * 16 + l15;
            int off = KEYS_OFF + (((lrow << 8) + (t * 64 + lk * 16)) ^ ((lrow & 7) << 4));
            short8 kfr = *(const short8*)(smem + off);
            #pragma unroll
            for (int kt = 0; kt < 4; ++kt)
                acc[kt] = __builtin_amdgcn_mfma_f32_16x16x32_bf16(bfr[t * 4 + kt], kfr, acc[kt], 0, 0, 0);
        }
        // leaky + pack: pa[kt] = bf16x4 of h1[n=kt*16+lk*4+j][s=l15]
        short4v pa[4];
        #pragma unroll
        for (int kt = 0; kt < 4; ++kt) {
            f32x4 c1q = *(const f32x4*)(c1s + w * 64 + kt * 16 + lk * 4);
            #pragma unroll
            for (int r = 0; r < 4; ++r) {
                float v = acc[kt][r] + c1q[r];
                v = (v >= 0.f) ? v : a1v * v;
                pa[kt][r] = (short)cvtbf(v);
            }
        }
        // layer 2: acc2[nt2] = h2^T: row = e_local(lk*4+r), col = s(l15)
        f32x4 acc2[2];
        acc2[0] = fz; acc2[1] = fz;
        #pragma unroll
        for (int kt = 0; kt < 4; ++kt) {
            acc2[0] = mfma16(w2a[0][kt], pa[kt], acc2[0]);
            acc2[1] = mfma16(w2a[1][kt], pa[kt], acc2[1]);
        }
        // layer 3: each lane sums its 8 e-values for s = l15; reduce over lk groups
        float sum = 0.f;
        #pragma unroll
        for (int nt2 = 0; nt2 < 2; ++nt2) {
            f32x4 b2q = *(const f32x4*)(b2s + w * 32 + nt2 * 16 + lk * 4);
            f32x4 w3q = *(const f32x4*)(w3s + w * 32 + nt2 * 16 + lk * 4);
            #pragma unroll
            for (int r = 0; r < 4; ++r) {
                float v = acc2[nt2][r] + b2q[r];
                v = (v >= 0.f) ? v : a2v * v;
                sum += v * w3q[r];
            }
        }
        sum += __shfl_xor(sum, 16);
        sum += __shfl_xor(sum, 32);
        // lanes 0..15 hold score for s = rbase + mi*16 + l15
        if (l < 16) {
            int sl = mi * 16 + l15;
            int sg = rbase + sl;
            if (sg < Ssz) {
                float tw = __expf(0.1f * (float)(sg - (Ssz - 1)));
                float sc = (sum + b3v) * tw;
                sc = kmask[bb * Ssz + sg] ? sc : -1.0e9f;
                scores_ws[bb * 800 + w * 200 + sg] = sc;
                scb[sl] = sc;
            } else {
                scb[sl] = -1.0e30f;
            }
        }
    }

    // ---- wave-local partial softmax + PV over this half's rows ----
    {
        int s0i = l, s1i = l + 64;
        bool v0 = (rbase + s0i < Ssz);
        bool v1 = (s1i < 112) && (rbase + s1i < Ssz);
        float x0 = v0 ? scb[s0i] : -1.0e30f;
        float x1 = v1 ? scb[s1i] : -1.0e30f;
        float m = fmaxf(x0, x1);
        #pragma unroll
        for (int mm = 1; mm < 64; mm <<= 1) m = fmaxf(m, __shfl_xor(m, mm));
        float e0 = v0 ? __expf(x0 - m) : 0.f;
        float e1 = v1 ? __expf(x1 - m) : 0.f;
        float dsum = e0 + e1;
        #pragma unroll
        for (int mm = 1; mm < 64; mm <<= 1) dsum += __shfl_xor(dsum, mm);
        scb[s0i] = e0;
        if (s1i < 112) scb[s1i] = e1;
        // PV split-s: lane -> (g = s-half, dq = d-quad); 56 iters of uint2 reads
        int g = l >> 5, dq = l & 31;
        float n0 = 0.f, n1 = 0.f, n2 = 0.f, n3 = 0.f;
        const int sb = g * 56;
        #pragma unroll 4
        for (int si = 0; si < 56; ++si) {
            int s = sb + si;
            float wv = scb[s];
            uint2 kv = *(const uint2*)(smem + KEYS_OFF + (((s << 8) + 8 * dq) ^ ((s & 7) << 4)));
            n0 += wv * bflo(kv.x);
            n1 += wv * bfhi(kv.x);
            n2 += wv * bflo(kv.y);
            n3 += wv * bfhi(kv.y);
        }
        n0 += __shfl_xor(n0, 32);
        n1 += __shfl_xor(n1, 32);
        n2 += __shfl_xor(n2, 32);
        n3 += __shfl_xor(n3, 32);
        if (l < 32) {
            size_t base = ((size_t)(bb * 4 + w) * 2 + half) * 128;   // numws: 16384 x 128 f32
            float4 o; o.x = n0; o.y = n1; o.z = n2; o.w = n3;
            *(float4*)(numws + base + 4 * dq) = o;
        }
        if (l == 0) {
            mdws[((bb * 4 + w) * 2 + half) * 2]     = m;
            mdws[((bb * 4 + w) * 2 + half) * 2 + 1] = dsum;
        }
    }
}

// ---------- kernel A (main path): bfr loaded from prefolded W1g2 ----------
__launch_bounds__(256, 3)
__global__ void scores_w1g(const float* __restrict__ keys, const int* __restrict__ kmask,
                           const float* __restrict__ a1, const float* __restrict__ b2,
                           const float* __restrict__ a2, const float* __restrict__ W3,
                           const float* __restrict__ b3,
                           const ushort_t* __restrict__ W2bf, const float* __restrict__ c1ws,
                           const ushort_t* __restrict__ W1g2, float* __restrict__ scores_ws,
                           float* __restrict__ numws, float* __restrict__ mdws) {
    extern __shared__ char smem[];
    const int tid  = threadIdx.x;
    const int bb   = blockIdx.x >> 1;
    const int half = blockIdx.x & 1;
    const int w   = tid >> 6;
    const int l   = tid & 63;
    const int l15 = l & 15;
    const int lk  = l >> 4;

    stage_all(smem, keys, c1ws, b2, W3, bb, half, tid);
    __builtin_amdgcn_sched_barrier(0);

    short8 bfr[16];
    const ushort_t* w1p = W1g2 + ((size_t)bb << 15);
    #pragma unroll
    for (int t = 0; t < 4; ++t)
        #pragma unroll
        for (int nt = 0; nt < 4; ++nt)
            bfr[t * 4 + nt] = *(const short8*)(w1p +
                (size_t)((t * 4 + lk) * 256 + w * 64 + nt * 16 + l15) * 8);

    scores_body(smem, bfr, kmask, a1, a2, b3, W2bf, scores_ws,
                numws, mdws, bb, half, w, l, l15, lk);
}

// ---------- kernel A (fallback, small ws): in-register fold at safe (256,2) ----------
__launch_bounds__(256, 2)
__global__ void scores_fold(const float* __restrict__ query, const float* __restrict__ keys,
                            const int* __restrict__ kmask,
                            const float* __restrict__ a1, const float* __restrict__ b2,
                            const float* __restrict__ a2, const float* __restrict__ W3,
                            const float* __restrict__ b3,
                            const float* __restrict__ W1sum, const float* __restrict__ W1c,
                            const ushort_t* __restrict__ W2bf, const float* __restrict__ c1ws,
                            float* __restrict__ scores_ws,
                            float* __restrict__ numws, float* __restrict__ mdws) {
    extern __shared__ char smem[];
    const int tid  = threadIdx.x;
    const int bb   = blockIdx.x >> 1;
    const int half = blockIdx.x & 1;
    const int w   = tid >> 6;
    const int l   = tid & 63;
    const int l15 = l & 15;
    const int lk  = l >> 4;

    stage_all(smem, keys, c1ws, b2, W3, bb, half, tid);
    __builtin_amdgcn_sched_barrier(0);

    short8 bfr[16];
    #pragma unroll
    for (int t = 0; t < 4; ++t) {
        const int k0 = t * 32 + lk * 8;
        const float4* pq = (const float4*)(query + bb * 128 + k0);
        float4 q0 = pq[0], q1 = pq[1];
        #pragma unroll
        for (int nt = 0; nt < 4; ++nt) {
            int n = w * 64 + nt * 16 + l15;
            const float4* ps = (const float4*)(W1sum + n * 128 + k0);
            const float4* pc = (const float4*)(W1c + n * 128 + k0);
            float4 s0 = ps[0], s1 = ps[1];
            float4 c0 = pc[0], c1f = pc[1];
            short8 ov;
            ov[0] = (short)cvtbf(s0.x + c0.x * q0.x);
            ov[1] = (short)cvtbf(s0.y + c0.y * q0.y);
            ov[2] = (short)cvtbf(s0.z + c0.z * q0.z);
            ov[3] = (short)cvtbf(s0.w + c0.w * q0.w);
            ov[4] = (short)cvtbf(s1.x + c1f.x * q1.x);
            ov[5] = (short)cvtbf(s1.y + c1f.y * q1.y);
            ov[6] = (short)cvtbf(s1.z + c1f.z * q1.z);
            ov[7] = (short)cvtbf(s1.w + c1f.w * q1.w);
            bfr[t * 4 + nt] = ov;
        }
    }

    scores_body(smem, bfr, kmask, a1, a2, b3, W2bf, scores_ws,
                numws, mdws, bb, half, w, l, l15, lk);
}

// ---------- kernel B: softmax (avg out) + half-combine PV + projection ----------
__launch_bounds__(256, 4)
__global__ void finish_comb(const float* __restrict__ scores_ws, const float* __restrict__ numws,
                            const float* __restrict__ mdws, const float* __restrict__ WoT,
                            const float* __restrict__ bo, float* __restrict__ out) {
    __shared__ float scw[4][224];
    __shared__ float comb[128];
    __shared__ float po2[2][128];

    const int tid = threadIdx.x;
    const int bb  = blockIdx.x;
    const int w   = tid >> 6;
    const int l   = tid & 63;

    // softmax per head (for avg_weights output only)
    {
        float xv[4], wv[4];
        float mx = -3.0e38f;
        #pragma unroll
        for (int i = 0; i < 4; ++i) {
            int s = l + 64 * i;
            xv[i] = (s < Ssz) ? scores_ws[bb * 800 + w * 200 + s] : -1.0e30f;
            mx = fmaxf(mx, xv[i]);
        }
        #pragma unroll
        for (int m = 1; m < 64; m <<= 1) mx = fmaxf(mx, __shfl_xor(mx, m));
        float sm = 0.f;
        #pragma unroll
        for (int i = 0; i < 4; ++i) {
            int s = l + 64 * i;
            wv[i] = (s < Ssz) ? __expf(xv[i] - mx) : 0.f;
            sm += wv[i];
        }
        #pragma unroll
        for (int m = 1; m < 64; m <<= 1) sm += __shfl_xor(sm, m);
        float inv = 1.0f / sm;
        #pragma unroll
        for (int i = 0; i < 4; ++i) {
            int s = l + 64 * i;
            if (s < Ssz) scw[w][s] = wv[i] * inv;
        }
    }
    __syncthreads();

    if (tid < Ssz) {
        float aw = 0.25f * (scw[0][tid] + scw[1][tid] + scw[2][tid] + scw[3][tid]);
        out[Bsz * Dsz + bb * Ssz + tid] = aw;
    }

    // combine per-half PV partials: comb[d] = mean_h (num0*a0 + num1*a1)/den
    if (tid < 128) {
        float c = 0.f;
        #pragma unroll
        for (int h = 0; h < 4; ++h) {
            int mb = ((bb * 4 + h) * 2) * 2;
            float m0 = mdws[mb], d0 = mdws[mb + 1];
            float m1 = mdws[mb + 2], d1 = mdws[mb + 3];
            float m = fmaxf(m0, m1);
            float a0 = __expf(m0 - m), a1 = __expf(m1 - m);
            float den = d0 * a0 + d1 * a1;
            size_t nb = (size_t)((bb * 4 + h) * 2) * 128;
            c += (numws[nb + tid] * a0 + numws[nb + 128 + tid] * a1) / den;
        }
        comb[tid] = 0.25f * c;
    }
    __syncthreads();

    // projection: 2 parts of 64 j each
    {
        int d = tid & 127, part = tid >> 7;
        float o = 0.f;
        const float* wp = WoT + (size_t)part * 64 * 128 + d;
        #pragma unroll 8
        for (int j = 0; j < 64; ++j) o += comb[part * 64 + j] * wp[j * 128];
        po2[part][d] = o;
    }
    __syncthreads();
    if (tid < 128) out[bb * Dsz + tid] = bo[tid] + po2[0][tid] + po2[1][tid];
}

// ws layout (bytes):
//   0         W1sum   131072
//   131072    W1c     131072
//   262144    W1diffR 131072
//   393216    WoT      65536
//   458752    W2bf     16384
//   475136    c1     2097152
//   2572288   scores 6553600
//   9125888   numws  8388608
//   17514496  mdws    131072
//   17645568  W1g2 134217728   => total 151,863,296 (guarded)
extern "C" void kernel_launch(void* const* d_in, const int* in_sizes, int n_in,
                              void* d_out, int out_size, void* d_ws, size_t ws_size,
                              hipStream_t stream) {
    const float* query = (const float*)d_in[0];
    const float* keys  = (const float*)d_in[1];
    const int*   kmask = (const int*)d_in[2];
    const float* W1    = (const float*)d_in[3];
    const float* b1    = (const float*)d_in[4];
    const float* a1    = (const float*)d_in[5];
    const float* W2    = (const float*)d_in[6];
    const float* b2    = (const float*)d_in[7];
    const float* a2    = (const float*)d_in[8];
    const float* W3    = (const float*)d_in[9];
    const float* b3    = (const float*)d_in[10];
    const float* Wo    = (const float*)d_in[11];
    const float* bo    = (const float*)d_in[12];
    float* out = (float*)d_out;

    char* ws = (char*)d_ws;
    float*    W1sum   = (float*)(ws);
    float*    W1c     = (float*)(ws + 131072);
    float*    W1diffR = (float*)(ws + 262144);
    float*    WoT     = (float*)(ws + 393216);
    ushort_t* W2bf    = (ushort_t*)(ws + 458752);
    float*    c1ws    = (float*)(ws + 475136);
    float*    scores  = (float*)(ws + 2572288);
    float*    numws   = (float*)(ws + 9125888);
    float*    mdws    = (float*)(ws + 17514496);
    ushort_t* W1g2    = (ushort_t*)(ws + 17645568);

    const bool useW1G = ws_size >= (size_t)17645568 + (size_t)Bsz * 32768 * 2;

    prep_kernel<<<128, 256, 0, stream>>>(W1, W2, Wo, W1sum, W1c, W1diffR, WoT, W2bf);

    if (useW1G) {
        hipFuncSetAttribute(reinterpret_cast<const void*>(scores_w1g),
                            hipFuncAttributeMaxDynamicSharedMemorySize, SMEM_A);
        w1effc1_kernel<<<Bsz, 256, 0, stream>>>(query, W1sum, W1c, W1diffR, b1, W1g2, c1ws);
        scores_w1g<<<Bsz * 2, 256, SMEM_A, stream>>>(keys, kmask, a1, b2, a2, W3, b3,
                                                     W2bf, c1ws, W1g2, scores, numws, mdws);
    } else {
        hipFuncSetAttribute(reinterpret_cast<const void*>(scores_fold),
                            hipFuncAttributeMaxDynamicSharedMemorySize, SMEM_A);
        c1_kernel<<<Bsz, 256, 0, stream>>>(query, W1diffR, b1, c1ws);
        scores_fold<<<Bsz * 2, 256, SMEM_A, stream>>>(query, keys, kmask, a1, b2, a2, W3, b3,
                                                      W1sum, W1c, W2bf, c1ws, scores,
                                                      numws, mdws);
    }
    finish_comb<<<Bsz, 256, 0, stream>>>(scores, numws, mdws, WoT, bo, out);
}